// Round 11
// baseline (29507.291 us; speedup 1.0000x reference)
//
#include <hip/hip_runtime.h>
#include <stdint.h>
#include <math.h>

// Problem dims
#define Bn 256
#define Sn 512
#define En 256
#define Hn 256
#define Gn 1024            // 4*H
#define NSTEP 511          // S-1 decoder steps
#define MASK_VAL -100000.0

// Verified rounds 1-3,7-10: partitionable threefry + f64 compute -> absmax=0.
#define PARTITIONABLE 1

// fast/exact logit divergence bound ~7e-5 worst case; trigger exact fallback
// below this top-2 gap (3.5x margin).
#define GAP_TRIG 5e-4

// ---------------------------------------------------------------- threefry
__device__ __forceinline__ uint32_t rotl32(uint32_t v, int d) {
  return (v << d) | (v >> (32 - d));
}

__device__ __forceinline__ void threefry2x32(uint32_t k0, uint32_t k1,
                                             uint32_t x0, uint32_t x1,
                                             uint32_t& o0, uint32_t& o1) {
  const uint32_t ks2 = k0 ^ k1 ^ 0x1BD11BDAu;
  x0 += k0; x1 += k1;
  x0 += x1; x1 = rotl32(x1, 13); x1 ^= x0;
  x0 += x1; x1 = rotl32(x1, 15); x1 ^= x0;
  x0 += x1; x1 = rotl32(x1, 26); x1 ^= x0;
  x0 += x1; x1 = rotl32(x1,  6); x1 ^= x0;
  x0 += k1; x1 += ks2 + 1u;
  x0 += x1; x1 = rotl32(x1, 17); x1 ^= x0;
  x0 += x1; x1 = rotl32(x1, 29); x1 ^= x0;
  x0 += x1; x1 = rotl32(x1, 16); x1 ^= x0;
  x0 += x1; x1 = rotl32(x1, 24); x1 ^= x0;
  x0 += ks2; x1 += k0 + 2u;
  x0 += x1; x1 = rotl32(x1, 13); x1 ^= x0;
  x0 += x1; x1 = rotl32(x1, 15); x1 ^= x0;
  x0 += x1; x1 = rotl32(x1, 26); x1 ^= x0;
  x0 += x1; x1 = rotl32(x1,  6); x1 ^= x0;
  x0 += k0; x1 += k1 + 3u;
  x0 += x1; x1 = rotl32(x1, 17); x1 ^= x0;
  x0 += x1; x1 = rotl32(x1, 29); x1 ^= x0;
  x0 += x1; x1 = rotl32(x1, 16); x1 ^= x0;
  x0 += x1; x1 = rotl32(x1, 24); x1 ^= x0;
  x0 += k1; x1 += ks2 + 4u;
  x0 += x1; x1 = rotl32(x1, 13); x1 ^= x0;
  x0 += x1; x1 = rotl32(x1, 15); x1 ^= x0;
  x0 += x1; x1 = rotl32(x1, 26); x1 ^= x0;
  x0 += x1; x1 = rotl32(x1,  6); x1 ^= x0;
  x0 += ks2; x1 += k0 + 5u;
  o0 = x0; o1 = x1;
}

__device__ __forceinline__ uint32_t random_word(uint32_t k0, uint32_t k1, uint32_t n) {
#if PARTITIONABLE
  uint32_t o0, o1;
  threefry2x32(k0, k1, 0u, n, o0, o1);
  return o0 ^ o1;
#else
  const uint32_t half = (Bn * Sn) / 2;
  uint32_t lane = (n < half) ? n : (n - half);
  uint32_t o0, o1;
  threefry2x32(k0, k1, lane, lane + half, o0, o1);
  return (n < half) ? o0 : o1;
#endif
}

__device__ __forceinline__ double sigmoid64(double x) {
  return 1.0 / (1.0 + exp(-x));
}

// fast f32 tanh: 1 - 2/(exp(2x)+1) via native v_exp_f32; |err| <~ 5e-7 abs.
__device__ __forceinline__ float tanh_fast(float x) {
  float e = __expf(2.0f * x);
  return 1.0f - 2.0f / (e + 1.0f);
}

// ---------------------------------------------------------------- prep
__global__ __launch_bounds__(256) void k_wihe(const float* __restrict__ wemb,
                                              const float* __restrict__ wih,
                                              const float* __restrict__ bih,
                                              const float* __restrict__ bhh,
                                              double* __restrict__ wihe,
                                              double* __restrict__ bias) {
  int j = blockIdx.x * blockDim.x + threadIdx.x;
  if (j >= Gn) return;
  double a0 = 0.0, a1 = 0.0;
  for (int e = 0; e < En; ++e) {
    double w = (double)wih[j * En + e];
    a0 += (double)wemb[e] * w;
    a1 += (double)wemb[En + e] * w;
  }
  wihe[j] = a0;
  wihe[Gn + j] = a1;
  bias[j] = (double)bih[j] + (double)bhh[j];
}

__global__ __launch_bounds__(256) void k_keys(uint32_t* __restrict__ keys) {
  int j = blockIdx.x * blockDim.x + threadIdx.x;
  if (j >= NSTEP) return;
#if PARTITIONABLE
  uint32_t o0, o1;
  threefry2x32(0u, 1u, 0u, (uint32_t)j, o0, o1);
  keys[2 * j] = o0; keys[2 * j + 1] = o1;
#else
  uint32_t w[2];
  #pragma unroll
  for (int q = 0; q < 2; ++q) {
    uint32_t m = (uint32_t)(2 * j + q);
    uint32_t lane = (m < NSTEP) ? m : (m - NSTEP);
    uint32_t o0, o1;
    threefry2x32(0u, 1u, lane, lane + NSTEP, o0, o1);
    w[q] = (m < NSTEP) ? o0 : o1;
  }
  keys[2 * j] = w[0]; keys[2 * j + 1] = w[1];
#endif
}

// dst[k][j] = src[j][k]  (256x256 f32 transpose: Wq, Wref)
__global__ __launch_bounds__(256) void k_t32(const float* __restrict__ src,
                                             float* __restrict__ dst) {
  int idx = blockIdx.x * blockDim.x + threadIdx.x;
  int k = idx >> 8, j = idx & 255;
  dst[idx] = src[j * Hn + k];
}

// dst[k][j] = src[j][k]  (Whh: 1024 rows j, 256 cols k -> 256 x 1024)
__global__ __launch_bounds__(256) void k_t32w(const float* __restrict__ src,
                                              float* __restrict__ dst) {
  int idx = blockIdx.x * blockDim.x + threadIdx.x;   // 256*1024 elems
  int k = idx >> 10, j = idx & 1023;
  dst[idx] = src[j * Hn + k];
}

__global__ __launch_bounds__(256) void k_init(float* __restrict__ out) {
  int idx = blockIdx.x * blockDim.x + threadIdx.x;
  if (idx < Bn) out[Bn * NSTEP + idx * Sn] = 0.0f;   // indices[:,0] = START
}

// ---------------------------------------------------------------- main
// Block b owns batch row b end-to-end (zero cross-block communication).
// Base = r10 (28.2 ms, absmax 0). r11 deltas:
//  1. logits: FAST pass (tanh_fast + f32 accumulate, same mapping/staging/
//     t-order as r10) + top-2 gap test; gap < GAP_TRIG -> EXACT recompute
//     (verbatim r10 inner loop). Decisions provably identical to r10;
//     logprob output moves ~1e-5 on untriggered rows only.
//  2. cell: double2 (b128) LDS reads of sh_h — bit-identical, half the LDS
//     issues. Recurrent k-ascending order untouched (numpy dgemm is k-serial
//     — that order is load-bearing; r9 lesson).
//  3. decoder x-load column via readfirstlane (block-uniform ch).
struct AttnS {
  double qpart[4][256];   // 8 KB
  double p2[2][512];      // 8 KB
  double sl[512];         // 4 KB
  double zz[512];         // 4 KB
  double sg[512];         // 4 KB  precomputed gumbel
  float  qf[256];
  float  vbuf[256];
};

__global__ __launch_bounds__(1024, 4) void k_main(
    const float* __restrict__ inp,
    const double* __restrict__ wihe_e, const double* __restrict__ bias_e,
    const float* __restrict__ whhT_e,
    const double* __restrict__ wihe_d, const double* __restrict__ bias_d,
    const float* __restrict__ whhT_d,
    const float* __restrict__ wrefT, const float* __restrict__ wqT,
    const float* __restrict__ v,
    float* __restrict__ refT,
    const uint32_t* __restrict__ keys,
    float* __restrict__ out) {
  __shared__ __align__(16) double sh_h[Hn];   // current h (f64)
  __shared__ double sh_g[Gn];                 // gates
  __shared__ AttnS at;
  __shared__ int smask[Sn];

  const int b   = blockIdx.x;
  const int tid = threadIdx.x;
  const int w   = tid >> 6;
  const int l   = tid & 63;

  // per-thread gate-row constants (j = tid)
  const double bj_e = bias_e[tid], w0e = wihe_e[tid], w1e = wihe_e[Gn + tid];
  const double bj_d = bias_d[tid], w0d = wihe_d[tid], w1d = wihe_d[Gn + tid];

  double creg = 0.0;              // c for unit u = tid (threads 0..255)
  if (tid < Hn) sh_h[tid] = 0.0;
  if (tid < Sn) smask[tid] = (tid == 0) ? 1 : 0;
  if (tid < Hn) at.vbuf[tid] = v[tid];
  __syncthreads();

  const float* wcol_e = whhT_e + tid;
  const float* wcol_d = whhT_d + tid;
  const int part = tid >> 8, tcol = tid & 255;

  // ================================================================ encoder
  for (int s = 0; s < Sn; ++s) {
    // cell: gate j = tid, exact k-ascending order (double2 reads, same math)
    {
      double x0 = (double)inp[((size_t)b * Sn + s) * 2 + 0];
      double x1 = (double)inp[((size_t)b * Sn + s) * 2 + 1];
      double acc = bj_e + x0 * w0e + x1 * w1e;
      #pragma unroll 4
      for (int k = 0; k < Hn; k += 2) {
        double2 hv = *(const double2*)&sh_h[k];
        acc += hv.x * (double)wcol_e[(size_t)k << 10];
        acc += hv.y * (double)wcol_e[(size_t)(k + 1) << 10];
      }
      sh_g[tid] = acc;
    }
    __syncthreads();                       // S1
    if (tid < Hn) {
      double gi = sh_g[tid];
      double gf = sh_g[256 + tid];
      double gg = sh_g[512 + tid];
      double go = sh_g[768 + tid];
      double cn = sigmoid64(gf) * creg + sigmoid64(gi) * tanh(gg);
      double hn = sigmoid64(go) * tanh(cn);
      creg = cn;
      sh_h[tid] = hn;
    }
    __syncthreads();                       // S2
    // refproj column s (verified split-k pattern, f64 h)
    {
      double racc = 0.0;
      #pragma unroll 8
      for (int i = 0; i < 64; ++i) {
        int k = part * 64 + i;
        racc += sh_h[k] * (double)wrefT[(size_t)k * Hn + tcol];
      }
      at.qpart[part][tcol] = racc;
    }
    __syncthreads();                       // S3
    if (tid < Hn) {
      double r = (at.qpart[0][tid] + at.qpart[1][tid]) +
                 (at.qpart[2][tid] + at.qpart[3][tid]);
      refT[((size_t)b * Hn + tid) * Sn + s] = (float)r;
    }
  }

  // ================================================================ decoder
  int ch = 0;   // START; every thread carries the chosen index in-register
  for (int t = 0; t < NSTEP; ++t) {
    // gumbel precompute (mask-independent; same-thread slot, no hazard)
    {
      const uint32_t k0 = keys[2 * t], k1 = keys[2 * t + 1];
      if (tid < Sn) {
        uint32_t wrd = random_word(k0, k1, (uint32_t)(b * Sn + tid));
        float uf = __uint_as_float((wrd >> 9) | 0x3f800000u) - 1.0f;
        uf = fmaxf(uf, 1.17549435e-38f);
        at.sg[tid] = -log(-log((double)uf));
      }
    }
    // cell (exact k-ascending order; double2 reads; uniform column scalar)
    {
      int col = __builtin_amdgcn_readfirstlane(ch);
      double x0 = (double)inp[((size_t)b * Sn + col) * 2 + 0];
      double x1 = (double)inp[((size_t)b * Sn + col) * 2 + 1];
      double acc = bj_d + x0 * w0d + x1 * w1d;
      #pragma unroll 4
      for (int k = 0; k < Hn; k += 2) {
        double2 hv = *(const double2*)&sh_h[k];
        acc += hv.x * (double)wcol_d[(size_t)k << 10];
        acc += hv.y * (double)wcol_d[(size_t)(k + 1) << 10];
      }
      sh_g[tid] = acc;
    }
    __syncthreads();                       // S1
    if (tid < Hn) {
      double gi = sh_g[tid];
      double gf = sh_g[256 + tid];
      double gg = sh_g[512 + tid];
      double go = sh_g[768 + tid];
      double cn = sigmoid64(gf) * creg + sigmoid64(gi) * tanh(gg);
      double hn = sigmoid64(go) * tanh(cn);
      creg = cn;
      sh_h[tid] = hn;
    }
    __syncthreads();                       // S2
    // q-projection (r10 pattern)
    {
      double qa = 0.0;
      #pragma unroll 8
      for (int i = 0; i < 64; ++i) {
        int k = part * 64 + i;
        qa += sh_h[k] * (double)wqT[(size_t)k * Hn + tcol];
      }
      at.qpart[part][tcol] = qa;
    }
    __syncthreads();                       // S3
    if (tid < Hn) {
      double q = (at.qpart[0][tid] + at.qpart[1][tid]) +
                 (at.qpart[2][tid] + at.qpart[3][tid]);
      at.qf[tid] = (float)q;
    }
    __syncthreads();                       // S4
    // FAST logits: r10 mapping/staging/t-order; tanh_fast + f32 accumulate
    const int sE = tid & 511, ph = tid >> 9;
    {
      const float* rT = refT + ((size_t)b * Hn + ph * 128) * Sn + sE;
      float la = 0.0f;
      for (int c = 0; c < 16; ++c) {
        float st[8];
        #pragma unroll
        for (int i = 0; i < 8; ++i)
          st[i] = rT[(size_t)(c * 8 + i) * Sn];
        #pragma unroll
        for (int i = 0; i < 8; ++i) {
          int t2 = ph * 128 + c * 8 + i;
          la += at.vbuf[t2] * tanh_fast(at.qf[t2] + st[i]);
        }
      }
      at.p2[ph][sE] = (double)la;
    }
    __syncthreads();                       // S5
    if (tid < Sn) {
      double lg = smask[tid] ? (double)MASK_VAL
                             : (at.p2[0][tid] + at.p2[1][tid]);
      at.sl[tid] = lg;
      at.zz[tid] = lg + at.sg[tid];
    }
    __syncthreads();                       // S6
    // top-2 over zz (ALL waves redundantly; identical sequence -> uniform)
    double z1, z2; int i1;
    {
      z1 = at.zz[l]; i1 = l; z2 = -1.0e300;
      #pragma unroll
      for (int k = 1; k < 8; ++k) {
        int s2 = l + k * 64;
        double zc = at.zz[s2];
        if (zc > z1 || (zc == z1 && s2 < i1)) { z2 = z1; z1 = zc; i1 = s2; }
        else if (zc > z2) z2 = zc;
      }
      #pragma unroll
      for (int m = 32; m >= 1; m >>= 1) {
        double oz1 = __shfl_xor(z1, m);
        int    oi1 = __shfl_xor(i1, m);
        double oz2 = __shfl_xor(z2, m);
        if (oz1 > z1 || (oz1 == z1 && oi1 < i1)) {
          z2 = fmax(z1, oz2); z1 = oz1; i1 = oi1;
        } else {
          z2 = fmax(z2, oz1);
        }
      }
    }
    if (z1 - z2 >= GAP_TRIG) {
      ch = i1;   // fast argmax provably equals exact argmax
    } else {
      // EXACT fallback: verbatim r10 logits (tanhf, f64 acc, same order)
      {
        const float* rT = refT + ((size_t)b * Hn + ph * 128) * Sn + sE;
        double la = 0.0;
        for (int c = 0; c < 16; ++c) {
          float st[8];
          #pragma unroll
          for (int i = 0; i < 8; ++i)
            st[i] = rT[(size_t)(c * 8 + i) * Sn];
          #pragma unroll
          for (int i = 0; i < 8; ++i) {
            int t2 = ph * 128 + c * 8 + i;
            float qv = at.qf[t2];
            double vv = (double)at.vbuf[t2];
            la += vv * (double)tanhf(qv + st[i]);
          }
        }
        at.p2[ph][sE] = la;
      }
      __syncthreads();                     // S6b
      if (tid < Sn) {
        double lg = smask[tid] ? (double)MASK_VAL
                               : (at.p2[0][tid] + at.p2[1][tid]);
        at.sl[tid] = lg;
        at.zz[tid] = lg + at.sg[tid];
      }
      __syncthreads();                     // S6c
      // exact argmax (r10 code, all waves)
      double bz = at.zz[l]; int bi = l;
      #pragma unroll
      for (int k = 1; k < 8; ++k) {
        int s2 = l + k * 64;
        double zc = at.zz[s2];
        if (zc > bz || (zc == bz && s2 < bi)) { bz = zc; bi = s2; }
      }
      #pragma unroll
      for (int m = 32; m >= 1; m >>= 1) {
        double oz = __shfl_xor(bz, m);
        int    oi = __shfl_xor(bi, m);
        if (oz > bz || (oz == bz && oi < bi)) { bz = oz; bi = oi; }
      }
      ch = bi;
    }
    // logsumexp (wave 1 only) + output writes + mask update
    if (w == 1) {
      double bm = at.sl[l];
      #pragma unroll
      for (int k = 1; k < 8; ++k) bm = fmax(bm, at.sl[l + k * 64]);
      #pragma unroll
      for (int m = 32; m >= 1; m >>= 1) bm = fmax(bm, __shfl_xor(bm, m));
      double ps = 0.0;
      #pragma unroll
      for (int k = 0; k < 8; ++k) ps += exp(at.sl[l + k * 64] - bm);
      #pragma unroll
      for (int m = 32; m >= 1; m >>= 1) ps += __shfl_xor(ps, m);
      if (l == 0) {
        double lse = bm + log(ps);
        double lp = at.sl[ch] - lse;
        out[(size_t)b * NSTEP + t] = (float)lp;
        out[(size_t)Bn * NSTEP + (size_t)b * Sn + (t + 1)] = (float)ch;
        smask[ch] = 1;
      }
    }
    // no trailing barrier: next step's S1..S5 separate smask/sl/zz hazards
  }
}

// ---------------------------------------------------------------- launch
extern "C" void kernel_launch(void* const* d_in, const int* in_sizes, int n_in,
                              void* d_out, int out_size, void* d_ws, size_t ws_size,
                              hipStream_t stream) {
  const float* inp  = (const float*)d_in[0];
  const float* wemb = (const float*)d_in[1];
  const float* eWih = (const float*)d_in[2];
  const float* eWhh = (const float*)d_in[3];
  const float* ebih = (const float*)d_in[4];
  const float* ebhh = (const float*)d_in[5];
  const float* dWih = (const float*)d_in[6];
  const float* dWhh = (const float*)d_in[7];
  const float* dbih = (const float*)d_in[8];
  const float* dbhh = (const float*)d_in[9];
  const float* Wq   = (const float*)d_in[10];
  const float* Wref = (const float*)d_in[11];
  const float* v    = (const float*)d_in[12];
  float* out = (float*)d_out;

  char* ws = (char*)d_ws;
  size_t off = 0;
  auto alloc = [&](size_t bytes) -> void* {
    void* p = (void*)(ws + off);
    off += (bytes + 255) & ~(size_t)255;
    return p;
  };
  // total ~137 MB (proven workspace level)
  float*    refT   = (float*)   alloc((size_t)Bn * Sn * Hn * sizeof(float));   // 134 MB
  float*    whhT_e = (float*)   alloc((size_t)Hn * Gn * sizeof(float));        // 1 MB
  float*    whhT_d = (float*)   alloc((size_t)Hn * Gn * sizeof(float));        // 1 MB
  float*    wqT    = (float*)   alloc((size_t)Hn * Hn * sizeof(float));
  float*    wrefT  = (float*)   alloc((size_t)Hn * Hn * sizeof(float));
  double*   wihe_e = (double*)  alloc(2 * Gn * sizeof(double));
  double*   wihe_d = (double*)  alloc(2 * Gn * sizeof(double));
  double*   bias_e = (double*)  alloc(Gn * sizeof(double));
  double*   bias_d = (double*)  alloc(Gn * sizeof(double));
  uint32_t* keys   = (uint32_t*)alloc(2 * NSTEP * sizeof(uint32_t));
  (void)ws_size; (void)in_sizes; (void)n_in; (void)out_size;

  k_wihe<<<Gn / 256, 256, 0, stream>>>(wemb, eWih, ebih, ebhh, wihe_e, bias_e);
  k_wihe<<<Gn / 256, 256, 0, stream>>>(wemb, dWih, dbih, dbhh, wihe_d, bias_d);
  k_keys<<<2, 256, 0, stream>>>(keys);
  k_t32<<<(Hn * Hn) / 256, 256, 0, stream>>>(Wq, wqT);
  k_t32<<<(Hn * Hn) / 256, 256, 0, stream>>>(Wref, wrefT);
  k_t32w<<<(Hn * Gn) / 256, 256, 0, stream>>>(eWhh, whhT_e);
  k_t32w<<<(Hn * Gn) / 256, 256, 0, stream>>>(dWhh, whhT_d);
  k_init<<<1, 256, 0, stream>>>(out);

  k_main<<<Bn, 1024, 0, stream>>>(
      inp, wihe_e, bias_e, whhT_e, wihe_d, bias_d, whhT_d,
      wrefT, wqT, v, refT, keys, out);
}

// Round 12
// 27800.961 us; speedup vs baseline: 1.0614x; 1.0614x over previous
//
#include <hip/hip_runtime.h>
#include <stdint.h>
#include <math.h>

// Problem dims
#define Bn 256
#define Sn 512
#define En 256
#define Hn 256
#define Gn 1024            // 4*H
#define NSTEP 511          // S-1 decoder steps
#define MASK_VAL -100000.0

// Verified rounds 1-3,7-11: partitionable threefry + f64 compute -> absmax=0.
#define PARTITIONABLE 1

// ---------------------------------------------------------------- threefry
__device__ __forceinline__ uint32_t rotl32(uint32_t v, int d) {
  return (v << d) | (v >> (32 - d));
}

__device__ __forceinline__ void threefry2x32(uint32_t k0, uint32_t k1,
                                             uint32_t x0, uint32_t x1,
                                             uint32_t& o0, uint32_t& o1) {
  const uint32_t ks2 = k0 ^ k1 ^ 0x1BD11BDAu;
  x0 += k0; x1 += k1;
  x0 += x1; x1 = rotl32(x1, 13); x1 ^= x0;
  x0 += x1; x1 = rotl32(x1, 15); x1 ^= x0;
  x0 += x1; x1 = rotl32(x1, 26); x1 ^= x0;
  x0 += x1; x1 = rotl32(x1,  6); x1 ^= x0;
  x0 += k1; x1 += ks2 + 1u;
  x0 += x1; x1 = rotl32(x1, 17); x1 ^= x0;
  x0 += x1; x1 = rotl32(x1, 29); x1 ^= x0;
  x0 += x1; x1 = rotl32(x1, 16); x1 ^= x0;
  x0 += x1; x1 = rotl32(x1, 24); x1 ^= x0;
  x0 += ks2; x1 += k0 + 2u;
  x0 += x1; x1 = rotl32(x1, 13); x1 ^= x0;
  x0 += x1; x1 = rotl32(x1, 15); x1 ^= x0;
  x0 += x1; x1 = rotl32(x1, 26); x1 ^= x0;
  x0 += x1; x1 = rotl32(x1,  6); x1 ^= x0;
  x0 += k0; x1 += k1 + 3u;
  x0 += x1; x1 = rotl32(x1, 17); x1 ^= x0;
  x0 += x1; x1 = rotl32(x1, 29); x1 ^= x0;
  x0 += x1; x1 = rotl32(x1, 16); x1 ^= x0;
  x0 += x1; x1 = rotl32(x1, 24); x1 ^= x0;
  x0 += k1; x1 += ks2 + 4u;
  x0 += x1; x1 = rotl32(x1, 13); x1 ^= x0;
  x0 += x1; x1 = rotl32(x1, 15); x1 ^= x0;
  x0 += x1; x1 = rotl32(x1, 26); x1 ^= x0;
  x0 += x1; x1 = rotl32(x1,  6); x1 ^= x0;
  x0 += ks2; x1 += k0 + 5u;
  o0 = x0; o1 = x1;
}

__device__ __forceinline__ uint32_t random_word(uint32_t k0, uint32_t k1, uint32_t n) {
#if PARTITIONABLE
  uint32_t o0, o1;
  threefry2x32(k0, k1, 0u, n, o0, o1);
  return o0 ^ o1;
#else
  const uint32_t half = (Bn * Sn) / 2;
  uint32_t lane = (n < half) ? n : (n - half);
  uint32_t o0, o1;
  threefry2x32(k0, k1, lane, lane + half, o0, o1);
  return (n < half) ? o0 : o1;
#endif
}

__device__ __forceinline__ double sigmoid64(double x) {
  return 1.0 / (1.0 + exp(-x));
}

// ---------------------------------------------------------------- prep
__global__ __launch_bounds__(256) void k_wihe(const float* __restrict__ wemb,
                                              const float* __restrict__ wih,
                                              const float* __restrict__ bih,
                                              const float* __restrict__ bhh,
                                              double* __restrict__ wihe,
                                              double* __restrict__ bias) {
  int j = blockIdx.x * blockDim.x + threadIdx.x;
  if (j >= Gn) return;
  double a0 = 0.0, a1 = 0.0;
  for (int e = 0; e < En; ++e) {
    double w = (double)wih[j * En + e];
    a0 += (double)wemb[e] * w;
    a1 += (double)wemb[En + e] * w;
  }
  wihe[j] = a0;
  wihe[Gn + j] = a1;
  bias[j] = (double)bih[j] + (double)bhh[j];
}

__global__ __launch_bounds__(256) void k_keys(uint32_t* __restrict__ keys) {
  int j = blockIdx.x * blockDim.x + threadIdx.x;
  if (j >= NSTEP) return;
#if PARTITIONABLE
  uint32_t o0, o1;
  threefry2x32(0u, 1u, 0u, (uint32_t)j, o0, o1);
  keys[2 * j] = o0; keys[2 * j + 1] = o1;
#else
  uint32_t w[2];
  #pragma unroll
  for (int q = 0; q < 2; ++q) {
    uint32_t m = (uint32_t)(2 * j + q);
    uint32_t lane = (m < NSTEP) ? m : (m - NSTEP);
    uint32_t o0, o1;
    threefry2x32(0u, 1u, lane, lane + NSTEP, o0, o1);
    w[q] = (m < NSTEP) ? o0 : o1;
  }
  keys[2 * j] = w[0]; keys[2 * j + 1] = w[1];
#endif
}

// dst[k][j] = src[j][k]  (256x256 f32 transpose: Wq, Wref)
__global__ __launch_bounds__(256) void k_t32(const float* __restrict__ src,
                                             float* __restrict__ dst) {
  int idx = blockIdx.x * blockDim.x + threadIdx.x;
  int k = idx >> 8, j = idx & 255;
  dst[idx] = src[j * Hn + k];
}

// dst[k][j] = src[j][k]  (Whh: 1024 rows j, 256 cols k -> 256 x 1024)
__global__ __launch_bounds__(256) void k_t32w(const float* __restrict__ src,
                                              float* __restrict__ dst) {
  int idx = blockIdx.x * blockDim.x + threadIdx.x;   // 256*1024 elems
  int k = idx >> 10, j = idx & 1023;
  dst[idx] = src[j * Hn + k];
}

__global__ __launch_bounds__(256) void k_init(float* __restrict__ out) {
  int idx = blockIdx.x * blockDim.x + threadIdx.x;
  if (idx < Bn) out[Bn * NSTEP + idx * Sn] = 0.0f;   // indices[:,0] = START
}

// ---------------------------------------------------------------- main
// Block b owns batch row b end-to-end (zero cross-block communication).
// Base = r10 (28.2 ms, absmax 0; r11's compute-side logit opt regressed —
// that phase is refT-memory-bound). r12 deltas, ALL bit-identical on the
// decision path:
//  1. pointwise spread: all 1024 threads transform their own gate
//     (sigmoid64/tanh, wave-uniform select) before S1; unit threads then do
//     only the combine + tanh(c). Same values, same expression tree.
//  2. inline sampling: mask lives in per-thread registers (every wave tracks
//     all 512 slots redundantly); zz/sl computed inline from p2 + double-
//     buffered gumbel sg[t&1] after S5. Removes S6 barrier + zz phase.
//     Identical compare sequence -> identical ch.
//  3. r11 micro-opts kept: double2 sh_h reads, readfirstlane column.
struct AttnS {
  double qpart[4][256];   // 8 KB
  double p2[2][512];      // 8 KB
  double sg[2][512];      // 8 KB  gumbel, double-buffered by t&1
  float  qf[256];
  float  vbuf[256];
};

__global__ __launch_bounds__(1024, 4) void k_main(
    const float* __restrict__ inp,
    const double* __restrict__ wihe_e, const double* __restrict__ bias_e,
    const float* __restrict__ whhT_e,
    const double* __restrict__ wihe_d, const double* __restrict__ bias_d,
    const float* __restrict__ whhT_d,
    const float* __restrict__ wrefT, const float* __restrict__ wqT,
    const float* __restrict__ v,
    float* __restrict__ refT,
    const uint32_t* __restrict__ keys,
    float* __restrict__ out) {
  __shared__ __align__(16) double sh_h[Hn];   // current h (f64)
  __shared__ double sh_g[Gn];                 // transformed gates
  __shared__ AttnS at;

  const int b   = blockIdx.x;
  const int tid = threadIdx.x;
  const int w   = tid >> 6;
  const int l   = tid & 63;
  const int gsel = tid >> 8;      // 0:i 1:f 2:g 3:o (wave-uniform)

  // per-thread gate-row constants (j = tid)
  const double bj_e = bias_e[tid], w0e = wihe_e[tid], w1e = wihe_e[Gn + tid];
  const double bj_d = bias_d[tid], w0d = wihe_d[tid], w1d = wihe_d[Gn + tid];

  double creg = 0.0;              // c for unit u = tid (threads 0..255)
  if (tid < Hn) sh_h[tid] = 0.0;
  if (tid < Hn) at.vbuf[tid] = v[tid];
  __syncthreads();

  const float* wcol_e = whhT_e + tid;
  const float* wcol_d = whhT_d + tid;
  const int part = tid >> 8, tcol = tid & 255;

  // ================================================================ encoder
  for (int s = 0; s < Sn; ++s) {
    // cell gates: exact k-ascending order (double2 reads, same math);
    // transform applied by the OWNING thread (same input -> same value)
    {
      double x0 = (double)inp[((size_t)b * Sn + s) * 2 + 0];
      double x1 = (double)inp[((size_t)b * Sn + s) * 2 + 1];
      double acc = bj_e + x0 * w0e + x1 * w1e;
      #pragma unroll 4
      for (int k = 0; k < Hn; k += 2) {
        double2 hv = *(const double2*)&sh_h[k];
        acc += hv.x * (double)wcol_e[(size_t)k << 10];
        acc += hv.y * (double)wcol_e[(size_t)(k + 1) << 10];
      }
      sh_g[tid] = (gsel == 2) ? tanh(acc) : sigmoid64(acc);
    }
    __syncthreads();                       // S1
    if (tid < Hn) {
      double ti = sh_g[tid];
      double tf = sh_g[256 + tid];
      double tg = sh_g[512 + tid];
      double to = sh_g[768 + tid];
      double cn = tf * creg + ti * tg;     // == sig(gf)*c + sig(gi)*tanh(gg)
      double hn = to * tanh(cn);
      creg = cn;
      sh_h[tid] = hn;
    }
    __syncthreads();                       // S2
    // refproj column s (verified split-k pattern, f64 h)
    {
      double racc = 0.0;
      #pragma unroll 8
      for (int i = 0; i < 64; ++i) {
        int k = part * 64 + i;
        racc += sh_h[k] * (double)wrefT[(size_t)k * Hn + tcol];
      }
      at.qpart[part][tcol] = racc;
    }
    __syncthreads();                       // S3
    if (tid < Hn) {
      double r = (at.qpart[0][tid] + at.qpart[1][tid]) +
                 (at.qpart[2][tid] + at.qpart[3][tid]);
      refT[((size_t)b * Hn + tid) * Sn + s] = (float)r;
    }
  }

  // ================================================================ decoder
  int ch = 0;                               // START; uniform across threads
  unsigned mbits = (l == 0) ? 1u : 0u;      // bit k: s = l + 64k masked
  for (int t = 0; t < NSTEP; ++t) {
    const int par = t & 1;
    // gumbel precompute (double-buffered; reads of sg[par^1] are past)
    {
      const uint32_t k0 = keys[2 * t], k1 = keys[2 * t + 1];
      if (tid < Sn) {
        uint32_t wrd = random_word(k0, k1, (uint32_t)(b * Sn + tid));
        float uf = __uint_as_float((wrd >> 9) | 0x3f800000u) - 1.0f;
        uf = fmaxf(uf, 1.17549435e-38f);
        at.sg[par][tid] = -log(-log((double)uf));
      }
    }
    // cell (exact k-ascending order; double2 reads; uniform column scalar)
    {
      int col = __builtin_amdgcn_readfirstlane(ch);
      double x0 = (double)inp[((size_t)b * Sn + col) * 2 + 0];
      double x1 = (double)inp[((size_t)b * Sn + col) * 2 + 1];
      double acc = bj_d + x0 * w0d + x1 * w1d;
      #pragma unroll 4
      for (int k = 0; k < Hn; k += 2) {
        double2 hv = *(const double2*)&sh_h[k];
        acc += hv.x * (double)wcol_d[(size_t)k << 10];
        acc += hv.y * (double)wcol_d[(size_t)(k + 1) << 10];
      }
      sh_g[tid] = (gsel == 2) ? tanh(acc) : sigmoid64(acc);
    }
    __syncthreads();                       // S1
    if (tid < Hn) {
      double ti = sh_g[tid];
      double tf = sh_g[256 + tid];
      double tg = sh_g[512 + tid];
      double to = sh_g[768 + tid];
      double cn = tf * creg + ti * tg;
      double hn = to * tanh(cn);
      creg = cn;
      sh_h[tid] = hn;
    }
    __syncthreads();                       // S2
    // q-projection (r10 pattern)
    {
      double qa = 0.0;
      #pragma unroll 8
      for (int i = 0; i < 64; ++i) {
        int k = part * 64 + i;
        qa += sh_h[k] * (double)wqT[(size_t)k * Hn + tcol];
      }
      at.qpart[part][tcol] = qa;
    }
    __syncthreads();                       // S3
    if (tid < Hn) {
      double q = (at.qpart[0][tid] + at.qpart[1][tid]) +
                 (at.qpart[2][tid] + at.qpart[3][tid]);
      at.qf[tid] = (float)q;
    }
    __syncthreads();                       // S4
    // logits: r10 exact (tanhf, f64 acc, t-ascending, 8-deep staging)
    {
      const int sE = tid & 511, ph = tid >> 9;
      const float* rT = refT + ((size_t)b * Hn + ph * 128) * Sn + sE;
      double la = 0.0;
      for (int c = 0; c < 16; ++c) {
        float st[8];
        #pragma unroll
        for (int i = 0; i < 8; ++i)
          st[i] = rT[(size_t)(c * 8 + i) * Sn];
        #pragma unroll
        for (int i = 0; i < 8; ++i) {
          int t2 = ph * 128 + c * 8 + i;
          float qv = at.qf[t2];
          double vv = (double)at.vbuf[t2];
          la += vv * (double)tanhf(qv + st[i]);
        }
      }
      at.p2[ph][sE] = la;
    }
    __syncthreads();                       // S5
    // inline sampling: zz/sl from p2 + sg with register masks.
    // Values and compare sequence bit-identical to r10.
    double slv[8];
    {
      #pragma unroll
      for (int k = 0; k < 8; ++k) {
        int s2 = l + k * 64;
        slv[k] = (mbits >> k) & 1u ? (double)MASK_VAL
                                   : (at.p2[0][s2] + at.p2[1][s2]);
      }
      double bz = slv[0] + at.sg[par][l];
      int bi = l;
      #pragma unroll
      for (int k = 1; k < 8; ++k) {
        int s2 = l + k * 64;
        double z2 = slv[k] + at.sg[par][s2];
        if (z2 > bz || (z2 == bz && s2 < bi)) { bz = z2; bi = s2; }
      }
      #pragma unroll
      for (int m = 32; m >= 1; m >>= 1) {
        double oz = __shfl_xor(bz, m);
        int    oi = __shfl_xor(bi, m);
        if (oz > bz || (oz == bz && oi < bi)) { bz = oz; bi = oi; }
      }
      ch = bi;
    }
    // logsumexp (wave 1 only) + output writes
    if (w == 1) {
      double bm = slv[0];
      #pragma unroll
      for (int k = 1; k < 8; ++k) bm = fmax(bm, slv[k]);
      #pragma unroll
      for (int m = 32; m >= 1; m >>= 1) bm = fmax(bm, __shfl_xor(bm, m));
      double ps = 0.0;
      #pragma unroll
      for (int k = 0; k < 8; ++k) ps += exp(slv[k] - bm);
      #pragma unroll
      for (int m = 32; m >= 1; m >>= 1) ps += __shfl_xor(ps, m);
      if (l == 0) {
        double lse = bm + log(ps);
        double slch = at.p2[0][ch] + at.p2[1][ch];   // ch is never masked
        double lp = slch - lse;
        out[(size_t)b * NSTEP + t] = (float)lp;
        out[(size_t)Bn * NSTEP + (size_t)b * Sn + (t + 1)] = (float)ch;
      }
    }
    // register mask update (every thread, every wave)
    if ((ch & 63) == l) mbits |= 1u << (ch >> 6);
    // no trailing barrier: next step's S1..S5 separate p2/sg/qf hazards;
    // sg double-buffer isolates the next gumbel write from this step's reads
  }
}

// ---------------------------------------------------------------- launch
extern "C" void kernel_launch(void* const* d_in, const int* in_sizes, int n_in,
                              void* d_out, int out_size, void* d_ws, size_t ws_size,
                              hipStream_t stream) {
  const float* inp  = (const float*)d_in[0];
  const float* wemb = (const float*)d_in[1];
  const float* eWih = (const float*)d_in[2];
  const float* eWhh = (const float*)d_in[3];
  const float* ebih = (const float*)d_in[4];
  const float* ebhh = (const float*)d_in[5];
  const float* dWih = (const float*)d_in[6];
  const float* dWhh = (const float*)d_in[7];
  const float* dbih = (const float*)d_in[8];
  const float* dbhh = (const float*)d_in[9];
  const float* Wq   = (const float*)d_in[10];
  const float* Wref = (const float*)d_in[11];
  const float* v    = (const float*)d_in[12];
  float* out = (float*)d_out;

  char* ws = (char*)d_ws;
  size_t off = 0;
  auto alloc = [&](size_t bytes) -> void* {
    void* p = (void*)(ws + off);
    off += (bytes + 255) & ~(size_t)255;
    return p;
  };
  // total ~137 MB (proven workspace level)
  float*    refT   = (float*)   alloc((size_t)Bn * Sn * Hn * sizeof(float));   // 134 MB
  float*    whhT_e = (float*)   alloc((size_t)Hn * Gn * sizeof(float));        // 1 MB
  float*    whhT_d = (float*)   alloc((size_t)Hn * Gn * sizeof(float));        // 1 MB
  float*    wqT    = (float*)   alloc((size_t)Hn * Hn * sizeof(float));
  float*    wrefT  = (float*)   alloc((size_t)Hn * Hn * sizeof(float));
  double*   wihe_e = (double*)  alloc(2 * Gn * sizeof(double));
  double*   wihe_d = (double*)  alloc(2 * Gn * sizeof(double));
  double*   bias_e = (double*)  alloc(Gn * sizeof(double));
  double*   bias_d = (double*)  alloc(Gn * sizeof(double));
  uint32_t* keys   = (uint32_t*)alloc(2 * NSTEP * sizeof(uint32_t));
  (void)ws_size; (void)in_sizes; (void)n_in; (void)out_size;

  k_wihe<<<Gn / 256, 256, 0, stream>>>(wemb, eWih, ebih, ebhh, wihe_e, bias_e);
  k_wihe<<<Gn / 256, 256, 0, stream>>>(wemb, dWih, dbih, dbhh, wihe_d, bias_d);
  k_keys<<<2, 256, 0, stream>>>(keys);
  k_t32<<<(Hn * Hn) / 256, 256, 0, stream>>>(Wq, wqT);
  k_t32<<<(Hn * Hn) / 256, 256, 0, stream>>>(Wref, wrefT);
  k_t32w<<<(Hn * Gn) / 256, 256, 0, stream>>>(eWhh, whhT_e);
  k_t32w<<<(Hn * Gn) / 256, 256, 0, stream>>>(dWhh, whhT_d);
  k_init<<<1, 256, 0, stream>>>(out);

  k_main<<<Bn, 1024, 0, stream>>>(
      inp, wihe_e, bias_e, whhT_e, wihe_d, bias_d, whhT_d,
      wrefT, wqT, v, refT, keys, out);
}